// Round 16
// baseline (259.811 us; speedup 1.0000x reference)
//
#include <hip/hip_runtime.h>
#include <hip/hip_bf16.h>

#define T_SEQ 8192
#define E 64
// 0.125 (1/sqrt(64)) * log2(e): softmax computed in exp2 domain
#define QSCALE 0.18033688f

typedef __attribute__((ext_vector_type(4))) float f32x4;
typedef __attribute__((ext_vector_type(8))) short bf16x8;

// 2^x via hardware v_exp_f32 (avoids glibc __exp2f macro collision)
__device__ __forceinline__ float hw_exp2(float x) {
    float r;
    asm("v_exp_f32 %0, %1" : "=v"(r) : "v"(x));
    return r;
}
// packed bf16 pair convert -> v_cvt_pk_bf16_f32 (a -> low16, b -> high16)
__device__ __forceinline__ unsigned pk2(float a, float b) {
    __hip_bfloat162 h = __float22bfloat162_rn(make_float2(a, b));
    union { __hip_bfloat162 h; unsigned u; } cv; cv.h = h;
    return cv.u;
}
__device__ __forceinline__ float bf_lo(unsigned u) {
    union { unsigned u; float f; } c; c.u = u << 16; return c.f;
}
__device__ __forceinline__ float bf_hi(unsigned u) {
    union { unsigned u; float f; } c; c.u = u & 0xFFFF0000u; return c.f;
}
union Frag { unsigned u[4]; bf16x8 v; };

// R10 champion (split-S 32 AGPR + defer-max, 4 blocks/CU) with ONLY the PV phase
// fused across the two query passes: each vf LDS read feeds both passes' MFMAs
// (32 -> 16 ds_read_b128 in PV). S phases byte-identical to R10.
__global__ __launch_bounds__(256, 4)
void la_kernel(const float* __restrict__ q, const float* __restrict__ k,
               const float* __restrict__ v, float* __restrict__ out) {
    // One 32KB buffer, time-shared: K (bf16, swz) -> V^T (bf16, swz) -> O (fp32, swz)
    __shared__ __align__(16) unsigned char smem[32768];
    unsigned short* KV = (unsigned short*)smem;
    float* OB = (float*)smem;

    const int raw  = blockIdx.x;
    // XCD-aware swizzle: adjacent buckets (shared halo) on same XCD
    const int work = (raw & 7) * 512 + (raw >> 3);
    const int bh = work >> 6;
    const int qb = work & 63;

    const int tid  = threadIdx.x;
    const int wv   = tid >> 6;
    const int lane = tid & 63;
    const int g    = lane >> 4;
    const int col  = lane & 15;

    const size_t base_kv = (size_t)bh * T_SEQ * E;
    const int k0 = (qb - 1) * 128;         // window start (may be negative)
    const int STT = (qb == 0) ? 8 : 0;     // first valid key-tile (pad mask)
    const int SKT = (qb == 0) ? 4 : 0;

    // ---- prefetch Q fragments for BOTH passes, scale folded into bf16 convert ----
    bf16x8 qf0[2], qf1[2];
    #pragma unroll
    for (int it = 0; it < 2; ++it) {
        #pragma unroll
        for (int kq = 0; kq < 2; ++kq) {
            const float* src = q + ((size_t)bh * T_SEQ + qb * 128 + wv * 32 + it * 16 + col) * E
                                 + g * 8 + kq * 32;
            float4 f0 = *(const float4*)(src);
            float4 f1 = *(const float4*)(src + 4);
            Frag fr;
            fr.u[0] = pk2(f0.x * QSCALE, f0.y * QSCALE);
            fr.u[1] = pk2(f0.z * QSCALE, f0.w * QSCALE);
            fr.u[2] = pk2(f1.x * QSCALE, f1.y * QSCALE);
            fr.u[3] = pk2(f1.z * QSCALE, f1.w * QSCALE);
            if (it) qf1[kq] = fr.v; else qf0[kq] = fr.v;
        }
    }

    // ---- stage K: fp32 global -> bf16 LDS row-major [j][e], swizzled ----
    {
        const int jr = tid >> 4;
        const int c4 = (tid & 15) * 4;
        #pragma unroll
        for (int t = 0; t < 16; ++t) {
            const int jj = jr + t * 16;
            const int gk = k0 + jj;
            float4 kvv = make_float4(0.f, 0.f, 0.f, 0.f);
            if (gk >= 0) kvv = *(const float4*)(k + base_kv + (size_t)gk * E + c4);
            uint2 pr;
            pr.x = pk2(kvv.x, kvv.y);
            pr.y = pk2(kvv.z, kvv.w);
            *(uint2*)(&KV[(jj * 64 + c4) ^ ((jj & 7) << 3)]) = pr;
        }
    }
    __syncthreads();

    unsigned P0[32], P1[32];
    float inv0, inv1;

    // ---- S phase: split halves, per-half max-sub, defer-max merge (exact softmax) ----
    auto s_phase = [&](const int it, const bf16x8* qf, unsigned* __restrict__ P, float& inv_out) {
        const int NT = 2 * wv + it + 9;   // tiles with any unmasked element (wave-uniform)
        f32x4 S[8];                        // 32 AGPRs, reused by both halves
        float mA = -3.0e38f, sA = 0.f;

        // ---- half A: tiles 0..7 — never causal-masked; absent when qb==0 ----
        if (STT == 0) {
            #pragma unroll
            for (int jt = 0; jt < 8; ++jt) S[jt] = (f32x4)0.f;
            #pragma unroll
            for (int jt = 0; jt < 8; ++jt) {
                const int j = jt * 16 + col;
                #pragma unroll
                for (int kq = 0; kq < 2; ++kq) {
                    const int e = g * 8 + kq * 32;
                    bf16x8 kf = *(const bf16x8*)(&KV[(j * 64 + e) ^ ((j & 7) << 3)]);
                    S[jt] = __builtin_amdgcn_mfma_f32_16x16x32_bf16(kf, qf[kq], S[jt], 0, 0, 0);
                }
            }
            #pragma unroll
            for (int jt = 0; jt < 8; ++jt)
                #pragma unroll
                for (int r = 0; r < 4; ++r) mA = fmaxf(mA, S[jt][r]);
            mA = fmaxf(mA, __shfl_xor(mA, 16, 64));
            mA = fmaxf(mA, __shfl_xor(mA, 32, 64));
            #pragma unroll
            for (int jt = 0; jt < 8; ++jt) {
                #pragma unroll
                for (int r = 0; r < 4; ++r) {
                    float p = hw_exp2(S[jt][r] - mA);
                    S[jt][r] = p;
                    sA += p;
                }
            }
            #pragma unroll
            for (int kt = 0; kt < 4; ++kt) {
                P[4*kt+0] = pk2(S[2*kt  ][0], S[2*kt  ][1]);
                P[4*kt+1] = pk2(S[2*kt  ][2], S[2*kt  ][3]);
                P[4*kt+2] = pk2(S[2*kt+1][0], S[2*kt+1][1]);
                P[4*kt+3] = pk2(S[2*kt+1][2], S[2*kt+1][3]);
            }
        } else {
            #pragma unroll
            for (int i2 = 0; i2 < 16; ++i2) P[i2] = 0u;
        }

        // ---- half B: tiles 8..NT-1 — only diag tile (NT-1) partially masked ----
        float mB = -3.0e38f, sB = 0.f;
        #pragma unroll
        for (int jt8 = 0; jt8 < 8; ++jt8) S[jt8] = (f32x4)0.f;
        #pragma unroll
        for (int jt8 = 0; jt8 < 8; ++jt8) {
            const int jt = 8 + jt8;
            if (jt < NT) {
                const int j = jt * 16 + col;
                #pragma unroll
                for (int kq = 0; kq < 2; ++kq) {
                    const int e = g * 8 + kq * 32;
                    bf16x8 kf = *(const bf16x8*)(&KV[(j * 64 + e) ^ ((j & 7) << 3)]);
                    S[jt8] = __builtin_amdgcn_mfma_f32_16x16x32_bf16(kf, qf[kq], S[jt8], 0, 0, 0);
                }
            }
        }
        #pragma unroll
        for (int jt8 = 0; jt8 < 8; ++jt8) {
            const int jt = 8 + jt8;
            if (jt < NT) {
                if (jt == NT - 1) {              // wave-uniform diag branch
                    #pragma unroll
                    for (int r = 0; r < 4; ++r) {
                        float s = (4 * g + r <= col) ? S[jt8][r] : -1.0e30f;
                        S[jt8][r] = s;
                        mB = fmaxf(mB, s);
                    }
                } else {
                    #pragma unroll
                    for (int r = 0; r < 4; ++r) mB = fmaxf(mB, S[jt8][r]);
                }
            }
        }
        mB = fmaxf(mB, __shfl_xor(mB, 16, 64));
        mB = fmaxf(mB, __shfl_xor(mB, 32, 64));
        // defer-max: keep mA unless mB exceeds it by >8 (P_B then bounded by 2^8)
        const float m = (mB <= mA + 8.f) ? mA : mB;
        #pragma unroll
        for (int jt8 = 0; jt8 < 8; ++jt8) {
            const int jt = 8 + jt8;
            if (jt < NT) {
                #pragma unroll
                for (int r = 0; r < 4; ++r) {
                    float p = hw_exp2(S[jt8][r] - m);
                    S[jt8][r] = p;
                    sB += p;
                }
            }
        }
        #pragma unroll
        for (int kt8 = 0; kt8 < 4; ++kt8) {
            P[16+4*kt8+0] = pk2(S[2*kt8  ][0], S[2*kt8  ][1]);
            P[16+4*kt8+1] = pk2(S[2*kt8  ][2], S[2*kt8  ][3]);
            P[16+4*kt8+2] = pk2(S[2*kt8+1][0], S[2*kt8+1][1]);
            P[16+4*kt8+3] = pk2(S[2*kt8+1][2], S[2*kt8+1][3]);
        }
        // rare rescale of half A when m moved to mB (never on typical data; zeros stay zero)
        if (__any(mB > mA + 8.f)) {
            const float scaleA = hw_exp2(mA - m);
            #pragma unroll
            for (int i2 = 0; i2 < 16; ++i2) {
                float a = bf_lo(P[i2]) * scaleA;
                float b = bf_hi(P[i2]) * scaleA;
                P[i2] = pk2(a, b);
            }
            sA *= scaleA;
        }
        float sum = sA + sB;
        sum += __shfl_xor(sum, 16, 64);
        sum += __shfl_xor(sum, 32, 64);
        inv_out = 1.0f / sum;
    };
    s_phase(0, qf0, P0, inv0);
    s_phase(1, qf1, P1, inv1);
    __syncthreads();   // all waves done reading K

    // ---- stage V: fp32 global -> bf16 LDS transposed [d][j], swizzled (overwrite K) ----
    // 2-lanes/bank write mapping: d-quad = tid>>4, key-pair = tid&15 (+16t)
    {
        const int d0 = (tid >> 4) * 4;
        const int pb = tid & 15;
        #pragma unroll
        for (int t = 0; t < 8; ++t) {
            const int p  = pb + 16 * t;
            const int gk = k0 + 2 * p;
            float4 a = make_float4(0.f,0.f,0.f,0.f), b = make_float4(0.f,0.f,0.f,0.f);
            if (gk >= 0) {
                a = *(const float4*)(v + base_kv + (size_t)gk * E + d0);
                b = *(const float4*)(v + base_kv + (size_t)(gk + 1) * E + d0);
            }
            const int jp = 2 * p;
            *(unsigned*)(&KV[((d0    ) * 256 + jp) ^ (((d0    ) & 7) << 3)]) = pk2(a.x, b.x);
            *(unsigned*)(&KV[((d0 + 1) * 256 + jp) ^ (((d0 + 1) & 7) << 3)]) = pk2(a.y, b.y);
            *(unsigned*)(&KV[((d0 + 2) * 256 + jp) ^ (((d0 + 2) & 7) << 3)]) = pk2(a.z, b.z);
            *(unsigned*)(&KV[((d0 + 3) * 256 + jp) ^ (((d0 + 3) & 7) << 3)]) = pk2(a.w, b.w);
        }
    }
    __syncthreads();

    // ---- PV fused: each vf LDS read feeds BOTH passes' MFMAs ----
    f32x4 O0[4], O1[4];
    #pragma unroll
    for (int dt = 0; dt < 4; ++dt) { O0[dt] = (f32x4)0.f; O1[dt] = (f32x4)0.f; }
    {
        const int s0 = ((g & 1) << 5) + col;
        const int s1 = s0 + 16;
        const bool hiSel = (g >= 2);
        const int NKT = wv + 5;
        #pragma unroll
        for (int kt = 0; kt < 8; ++kt) {
            if (kt >= SKT && kt < NKT) {
                Frag af0, af1;
                {
                    const unsigned x0 = P0[4*kt+0], x1 = P0[4*kt+1], y0 = P0[4*kt+2], y1 = P0[4*kt+3];
                    unsigned t0x = (unsigned)__shfl((int)x0, s0, 64), t0y = (unsigned)__shfl((int)y0, s0, 64);
                    unsigned t1x = (unsigned)__shfl((int)x1, s0, 64), t1y = (unsigned)__shfl((int)y1, s0, 64);
                    unsigned t2x = (unsigned)__shfl((int)x0, s1, 64), t2y = (unsigned)__shfl((int)y0, s1, 64);
                    unsigned t3x = (unsigned)__shfl((int)x1, s1, 64), t3y = (unsigned)__shfl((int)y1, s1, 64);
                    af0.u[0] = hiSel ? t0y : t0x;
                    af0.u[1] = hiSel ? t1y : t1x;
                    af0.u[2] = hiSel ? t2y : t2x;
                    af0.u[3] = hiSel ? t3y : t3x;
                }
                {
                    const unsigned x0 = P1[4*kt+0], x1 = P1[4*kt+1], y0 = P1[4*kt+2], y1 = P1[4*kt+3];
                    unsigned t0x = (unsigned)__shfl((int)x0, s0, 64), t0y = (unsigned)__shfl((int)y0, s0, 64);
                    unsigned t1x = (unsigned)__shfl((int)x1, s0, 64), t1y = (unsigned)__shfl((int)y1, s0, 64);
                    unsigned t2x = (unsigned)__shfl((int)x0, s1, 64), t2y = (unsigned)__shfl((int)y0, s1, 64);
                    unsigned t3x = (unsigned)__shfl((int)x1, s1, 64), t3y = (unsigned)__shfl((int)y1, s1, 64);
                    af1.u[0] = hiSel ? t0y : t0x;
                    af1.u[1] = hiSel ? t1y : t1x;
                    af1.u[2] = hiSel ? t2y : t2x;
                    af1.u[3] = hiSel ? t3y : t3x;
                }
                const int j0 = kt * 32 + g * 8;
                #pragma unroll
                for (int dt = 0; dt < 4; ++dt) {
                    const int d = dt * 16 + col;
                    bf16x8 vf = *(const bf16x8*)(&KV[(d * 256 + j0) ^ ((d & 7) << 3)]);
                    O0[dt] = __builtin_amdgcn_mfma_f32_16x16x32_bf16(af0.v, vf, O0[dt], 0, 0, 0);
                    O1[dt] = __builtin_amdgcn_mfma_f32_16x16x32_bf16(af1.v, vf, O1[dt], 0, 0, 0);
                }
            }
        }
    }
    __syncthreads();   // all waves done reading V

    // ---- per-output-row 1/sum via shfl (row 4g+r's inv lives at lane with col==4g+r) ----
    const int srcbase = (lane & 48) | ((4 * (lane >> 4)) & 15);
    float w0[4], w1[4];
    #pragma unroll
    for (int r = 0; r < 4; ++r) {
        w0[r] = __shfl(inv0, srcbase + r, 64);
        w1[r] = __shfl(inv1, srcbase + r, 64);
    }

    // ---- bounce O through LDS (fp32, swizzled) for coalesced float4 stores ----
    #pragma unroll
    for (int it2 = 0; it2 < 2; ++it2) {
        const f32x4* O = it2 ? O1 : O0;
        const float* w = it2 ? w1 : w0;
        #pragma unroll
        for (int dt = 0; dt < 4; ++dt) {
            #pragma unroll
            for (int r = 0; r < 4; ++r) {
                const int row = wv * 32 + it2 * 16 + g * 4 + r;
                const int d = dt * 16 + col;
                OB[(row * 64 + d) ^ ((row & 7) << 2)] = O[dt][r] * w[r];
            }
        }
    }
    __syncthreads();
    {
        #pragma unroll
        for (int t = 0; t < 8; ++t) {
            const int f4  = t * 256 + tid;
            const int row = f4 >> 4;          // local row 0..127
            const int c4  = (f4 & 15) * 4;
            float4 val = *(const float4*)(&OB[(row * 64 + c4) ^ ((row & 7) << 2)]);
            *(float4*)(out + ((size_t)bh * T_SEQ + qb * 128 + row) * E + c4) = val;
        }
    }
}

extern "C" void kernel_launch(void* const* d_in, const int* in_sizes, int n_in,
                              void* d_out, int out_size, void* d_ws, size_t ws_size,
                              hipStream_t stream) {
    const float* q = (const float*)d_in[0];
    const float* k = (const float*)d_in[1];
    const float* v = (const float*)d_in[2];
    float* out = (float*)d_out;
    la_kernel<<<dim3(64 * 64), dim3(256), 0, stream>>>(q, k, v, out);
}

// Round 17
// 132.214 us; speedup vs baseline: 1.9651x; 1.9651x over previous
//
#include <hip/hip_runtime.h>
#include <hip/hip_bf16.h>

#define T_SEQ 8192
#define E 64
// 0.125 (1/sqrt(64)) * log2(e): softmax computed in exp2 domain
#define QSCALE 0.18033688f

typedef __attribute__((ext_vector_type(4))) float f32x4;
typedef __attribute__((ext_vector_type(8))) short bf16x8;

// 2^x via hardware v_exp_f32 (avoids glibc __exp2f macro collision)
__device__ __forceinline__ float hw_exp2(float x) {
    float r;
    asm("v_exp_f32 %0, %1" : "=v"(r) : "v"(x));
    return r;
}
// packed bf16 pair convert -> v_cvt_pk_bf16_f32 (a -> low16, b -> high16)
__device__ __forceinline__ unsigned pk2(float a, float b) {
    __hip_bfloat162 h = __float22bfloat162_rn(make_float2(a, b));
    union { __hip_bfloat162 h; unsigned u; } cv; cv.h = h;
    return cv.u;
}
__device__ __forceinline__ float bf_lo(unsigned u) {
    union { unsigned u; float f; } c; c.u = u << 16; return c.f;
}
__device__ __forceinline__ float bf_hi(unsigned u) {
    union { unsigned u; float f; } c; c.u = u & 0xFFFF0000u; return c.f;
}
union Frag { unsigned u[4]; bf16x8 v; };

// R10 champion (split-S 32 AGPR + defer-max merge, 4 blocks/CU) + wave-uniform
// staging specialization: qb>0 blocks (4032 of 4096) skip all bounds checks.
__global__ __launch_bounds__(256, 4)
void la_kernel(const float* __restrict__ q, const float* __restrict__ k,
               const float* __restrict__ v, float* __restrict__ out) {
    // One 32KB buffer, time-shared: K (bf16, swz) -> V^T (bf16, swz) -> O (fp32, swz)
    __shared__ __align__(16) unsigned char smem[32768];
    unsigned short* KV = (unsigned short*)smem;
    float* OB = (float*)smem;

    const int raw  = blockIdx.x;
    // XCD-aware swizzle: adjacent buckets (shared halo) on same XCD
    const int work = (raw & 7) * 512 + (raw >> 3);
    const int bh = work >> 6;
    const int qb = work & 63;

    const int tid  = threadIdx.x;
    const int wv   = tid >> 6;
    const int lane = tid & 63;
    const int g    = lane >> 4;
    const int col  = lane & 15;

    const size_t base_kv = (size_t)bh * T_SEQ * E;
    const int k0 = (qb - 1) * 128;         // window start (negative only when qb==0)
    const int STT = (qb == 0) ? 8 : 0;     // first valid key-tile (pad mask)
    const int SKT = (qb == 0) ? 4 : 0;

    // ---- prefetch Q fragments for BOTH passes, scale folded into bf16 convert ----
    bf16x8 qf0[2], qf1[2];
    #pragma unroll
    for (int it = 0; it < 2; ++it) {
        #pragma unroll
        for (int kq = 0; kq < 2; ++kq) {
            const float* src = q + ((size_t)bh * T_SEQ + qb * 128 + wv * 32 + it * 16 + col) * E
                                 + g * 8 + kq * 32;
            float4 f0 = *(const float4*)(src);
            float4 f1 = *(const float4*)(src + 4);
            Frag fr;
            fr.u[0] = pk2(f0.x * QSCALE, f0.y * QSCALE);
            fr.u[1] = pk2(f0.z * QSCALE, f0.w * QSCALE);
            fr.u[2] = pk2(f1.x * QSCALE, f1.y * QSCALE);
            fr.u[3] = pk2(f1.z * QSCALE, f1.w * QSCALE);
            if (it) qf1[kq] = fr.v; else qf0[kq] = fr.v;
        }
    }

    // ---- stage K: fp32 global -> bf16 LDS row-major [j][e], swizzled ----
    {
        const int jr = tid >> 4;
        const int c4 = (tid & 15) * 4;
        if (qb > 0) {                      // wave-uniform: no bounds checks needed
            const float* krow = k + base_kv + (size_t)k0 * E + (size_t)jr * E + c4;
            #pragma unroll
            for (int t = 0; t < 16; ++t) {
                const int jj = jr + t * 16;
                float4 kvv = *(const float4*)(krow + (size_t)t * 16 * E);
                uint2 pr;
                pr.x = pk2(kvv.x, kvv.y);
                pr.y = pk2(kvv.z, kvv.w);
                *(uint2*)(&KV[(jj * 64 + c4) ^ ((jj & 7) << 3)]) = pr;
            }
        } else {
            #pragma unroll
            for (int t = 0; t < 16; ++t) {
                const int jj = jr + t * 16;
                const int gk = k0 + jj;
                float4 kvv = make_float4(0.f, 0.f, 0.f, 0.f);
                if (gk >= 0) kvv = *(const float4*)(k + base_kv + (size_t)gk * E + c4);
                uint2 pr;
                pr.x = pk2(kvv.x, kvv.y);
                pr.y = pk2(kvv.z, kvv.w);
                *(uint2*)(&KV[(jj * 64 + c4) ^ ((jj & 7) << 3)]) = pr;
            }
        }
    }
    __syncthreads();

    unsigned P0[32], P1[32];
    float inv0, inv1;

    // ---- S phase: split halves, per-half max-sub, defer-max merge (exact softmax) ----
    auto s_phase = [&](const int it, const bf16x8* qf, unsigned* __restrict__ P, float& inv_out) {
        const int NT = 2 * wv + it + 9;   // tiles with any unmasked element (wave-uniform)
        f32x4 S[8];                        // 32 AGPRs, reused by both halves
        float mA = -3.0e38f, sA = 0.f;

        // ---- half A: tiles 0..7 — never causal-masked; absent when qb==0 ----
        if (STT == 0) {
            #pragma unroll
            for (int jt = 0; jt < 8; ++jt) S[jt] = (f32x4)0.f;
            #pragma unroll
            for (int jt = 0; jt < 8; ++jt) {
                const int j = jt * 16 + col;
                #pragma unroll
                for (int kq = 0; kq < 2; ++kq) {
                    const int e = g * 8 + kq * 32;
                    bf16x8 kf = *(const bf16x8*)(&KV[(j * 64 + e) ^ ((j & 7) << 3)]);
                    S[jt] = __builtin_amdgcn_mfma_f32_16x16x32_bf16(kf, qf[kq], S[jt], 0, 0, 0);
                }
            }
            #pragma unroll
            for (int jt = 0; jt < 8; ++jt)
                #pragma unroll
                for (int r = 0; r < 4; ++r) mA = fmaxf(mA, S[jt][r]);
            mA = fmaxf(mA, __shfl_xor(mA, 16, 64));
            mA = fmaxf(mA, __shfl_xor(mA, 32, 64));
            #pragma unroll
            for (int jt = 0; jt < 8; ++jt) {
                #pragma unroll
                for (int r = 0; r < 4; ++r) {
                    float p = hw_exp2(S[jt][r] - mA);
                    S[jt][r] = p;
                    sA += p;
                }
            }
            #pragma unroll
            for (int kt = 0; kt < 4; ++kt) {
                P[4*kt+0] = pk2(S[2*kt  ][0], S[2*kt  ][1]);
                P[4*kt+1] = pk2(S[2*kt  ][2], S[2*kt  ][3]);
                P[4*kt+2] = pk2(S[2*kt+1][0], S[2*kt+1][1]);
                P[4*kt+3] = pk2(S[2*kt+1][2], S[2*kt+1][3]);
            }
        } else {
            #pragma unroll
            for (int i2 = 0; i2 < 16; ++i2) P[i2] = 0u;
        }

        // ---- half B: tiles 8..NT-1 — only diag tile (NT-1) partially masked ----
        float mB = -3.0e38f, sB = 0.f;
        #pragma unroll
        for (int jt8 = 0; jt8 < 8; ++jt8) S[jt8] = (f32x4)0.f;
        #pragma unroll
        for (int jt8 = 0; jt8 < 8; ++jt8) {
            const int jt = 8 + jt8;
            if (jt < NT) {
                const int j = jt * 16 + col;
                #pragma unroll
                for (int kq = 0; kq < 2; ++kq) {
                    const int e = g * 8 + kq * 32;
                    bf16x8 kf = *(const bf16x8*)(&KV[(j * 64 + e) ^ ((j & 7) << 3)]);
                    S[jt8] = __builtin_amdgcn_mfma_f32_16x16x32_bf16(kf, qf[kq], S[jt8], 0, 0, 0);
                }
            }
        }
        #pragma unroll
        for (int jt8 = 0; jt8 < 8; ++jt8) {
            const int jt = 8 + jt8;
            if (jt < NT) {
                if (jt == NT - 1) {              // wave-uniform diag branch
                    #pragma unroll
                    for (int r = 0; r < 4; ++r) {
                        float s = (4 * g + r <= col) ? S[jt8][r] : -1.0e30f;
                        S[jt8][r] = s;
                        mB = fmaxf(mB, s);
                    }
                } else {
                    #pragma unroll
                    for (int r = 0; r < 4; ++r) mB = fmaxf(mB, S[jt8][r]);
                }
            }
        }
        mB = fmaxf(mB, __shfl_xor(mB, 16, 64));
        mB = fmaxf(mB, __shfl_xor(mB, 32, 64));
        // defer-max: keep mA unless mB exceeds it by >8 (P_B then bounded by 2^8)
        const float m = (mB <= mA + 8.f) ? mA : mB;
        #pragma unroll
        for (int jt8 = 0; jt8 < 8; ++jt8) {
            const int jt = 8 + jt8;
            if (jt < NT) {
                #pragma unroll
                for (int r = 0; r < 4; ++r) {
                    float p = hw_exp2(S[jt8][r] - m);
                    S[jt8][r] = p;
                    sB += p;
                }
            }
        }
        #pragma unroll
        for (int kt8 = 0; kt8 < 4; ++kt8) {
            P[16+4*kt8+0] = pk2(S[2*kt8  ][0], S[2*kt8  ][1]);
            P[16+4*kt8+1] = pk2(S[2*kt8  ][2], S[2*kt8  ][3]);
            P[16+4*kt8+2] = pk2(S[2*kt8+1][0], S[2*kt8+1][1]);
            P[16+4*kt8+3] = pk2(S[2*kt8+1][2], S[2*kt8+1][3]);
        }
        // rare rescale of half A when m moved to mB (never on typical data; zeros stay zero)
        if (__any(mB > mA + 8.f)) {
            const float scaleA = hw_exp2(mA - m);
            #pragma unroll
            for (int i2 = 0; i2 < 16; ++i2) {
                float a = bf_lo(P[i2]) * scaleA;
                float b = bf_hi(P[i2]) * scaleA;
                P[i2] = pk2(a, b);
            }
            sA *= scaleA;
        }
        float sum = sA + sB;
        sum += __shfl_xor(sum, 16, 64);
        sum += __shfl_xor(sum, 32, 64);
        inv_out = 1.0f / sum;
    };
    s_phase(0, qf0, P0, inv0);
    s_phase(1, qf1, P1, inv1);
    __syncthreads();   // all waves done reading K

    // ---- stage V: fp32 global -> bf16 LDS transposed [d][j], swizzled (overwrite K) ----
    // 2-lanes/bank write mapping: d-quad = tid>>4, key-pair = tid&15 (+16t)
    {
        const int d0 = (tid >> 4) * 4;
        const int pb = tid & 15;
        if (qb > 0) {                      // wave-uniform: no bounds checks needed
            const float* vrow = v + base_kv + (size_t)k0 * E + d0;
            #pragma unroll
            for (int t = 0; t < 8; ++t) {
                const int p  = pb + 16 * t;
                float4 a = *(const float4*)(vrow + (size_t)(2 * p) * E);
                float4 b = *(const float4*)(vrow + (size_t)(2 * p + 1) * E);
                const int jp = 2 * p;
                *(unsigned*)(&KV[((d0    ) * 256 + jp) ^ (((d0    ) & 7) << 3)]) = pk2(a.x, b.x);
                *(unsigned*)(&KV[((d0 + 1) * 256 + jp) ^ (((d0 + 1) & 7) << 3)]) = pk2(a.y, b.y);
                *(unsigned*)(&KV[((d0 + 2) * 256 + jp) ^ (((d0 + 2) & 7) << 3)]) = pk2(a.z, b.z);
                *(unsigned*)(&KV[((d0 + 3) * 256 + jp) ^ (((d0 + 3) & 7) << 3)]) = pk2(a.w, b.w);
            }
        } else {
            #pragma unroll
            for (int t = 0; t < 8; ++t) {
                const int p  = pb + 16 * t;
                const int gk = k0 + 2 * p;
                float4 a = make_float4(0.f,0.f,0.f,0.f), b = make_float4(0.f,0.f,0.f,0.f);
                if (gk >= 0) {
                    a = *(const float4*)(v + base_kv + (size_t)gk * E + d0);
                    b = *(const float4*)(v + base_kv + (size_t)(gk + 1) * E + d0);
                }
                const int jp = 2 * p;
                *(unsigned*)(&KV[((d0    ) * 256 + jp) ^ (((d0    ) & 7) << 3)]) = pk2(a.x, b.x);
                *(unsigned*)(&KV[((d0 + 1) * 256 + jp) ^ (((d0 + 1) & 7) << 3)]) = pk2(a.y, b.y);
                *(unsigned*)(&KV[((d0 + 2) * 256 + jp) ^ (((d0 + 2) & 7) << 3)]) = pk2(a.z, b.z);
                *(unsigned*)(&KV[((d0 + 3) * 256 + jp) ^ (((d0 + 3) & 7) << 3)]) = pk2(a.w, b.w);
            }
        }
    }
    __syncthreads();

    // ---- PV: O = P * V (unnormalized; 1/sum at epilogue) ----
    auto pv_phase = [&](const unsigned* __restrict__ P, f32x4* __restrict__ O) {
        #pragma unroll
        for (int dt = 0; dt < 4; ++dt) O[dt] = (f32x4)0.f;
        const int s0 = ((g & 1) << 5) + col;
        const int s1 = s0 + 16;
        const bool hiSel = (g >= 2);
        const int NKT = wv + 5;
        #pragma unroll
        for (int kt = 0; kt < 8; ++kt) {
            if (kt >= SKT && kt < NKT) {
                const unsigned x0 = P[4*kt+0], x1 = P[4*kt+1], y0 = P[4*kt+2], y1 = P[4*kt+3];
                unsigned t0x = (unsigned)__shfl((int)x0, s0, 64), t0y = (unsigned)__shfl((int)y0, s0, 64);
                unsigned t1x = (unsigned)__shfl((int)x1, s0, 64), t1y = (unsigned)__shfl((int)y1, s0, 64);
                unsigned t2x = (unsigned)__shfl((int)x0, s1, 64), t2y = (unsigned)__shfl((int)y0, s1, 64);
                unsigned t3x = (unsigned)__shfl((int)x1, s1, 64), t3y = (unsigned)__shfl((int)y1, s1, 64);
                Frag af;
                af.u[0] = hiSel ? t0y : t0x;
                af.u[1] = hiSel ? t1y : t1x;
                af.u[2] = hiSel ? t2y : t2x;
                af.u[3] = hiSel ? t3y : t3x;
                const int j0 = kt * 32 + g * 8;
                #pragma unroll
                for (int dt = 0; dt < 4; ++dt) {
                    const int d = dt * 16 + col;
                    bf16x8 vf = *(const bf16x8*)(&KV[(d * 256 + j0) ^ ((d & 7) << 3)]);
                    O[dt] = __builtin_amdgcn_mfma_f32_16x16x32_bf16(af.v, vf, O[dt], 0, 0, 0);
                }
            }
        }
    };
    f32x4 O0[4], O1[4];
    pv_phase(P0, O0);
    pv_phase(P1, O1);
    __syncthreads();   // all waves done reading V

    // ---- per-output-row 1/sum via shfl (row 4g+r's inv lives at lane with col==4g+r) ----
    const int srcbase = (lane & 48) | ((4 * (lane >> 4)) & 15);
    float w0[4], w1[4];
    #pragma unroll
    for (int r = 0; r < 4; ++r) {
        w0[r] = __shfl(inv0, srcbase + r, 64);
        w1[r] = __shfl(inv1, srcbase + r, 64);
    }

    // ---- bounce O through LDS (fp32, swizzled) for coalesced float4 stores ----
    #pragma unroll
    for (int it2 = 0; it2 < 2; ++it2) {
        const f32x4* O = it2 ? O1 : O0;
        const float* w = it2 ? w1 : w0;
        #pragma unroll
        for (int dt = 0; dt < 4; ++dt) {
            #pragma unroll
            for (int r = 0; r < 4; ++r) {
                const int row = wv * 32 + it2 * 16 + g * 4 + r;
                const int d = dt * 16 + col;
                OB[(row * 64 + d) ^ ((row & 7) << 2)] = O[dt][r] * w[r];
            }
        }
    }
    __syncthreads();
    {
        #pragma unroll
        for (int t = 0; t < 8; ++t) {
            const int f4  = t * 256 + tid;
            const int row = f4 >> 4;          // local row 0..127
            const int c4  = (f4 & 15) * 4;
            float4 val = *(const float4*)(&OB[(row * 64 + c4) ^ ((row & 7) << 2)]);
            *(float4*)(out + ((size_t)bh * T_SEQ + qb * 128 + row) * E + c4) = val;
        }
    }
}

extern "C" void kernel_launch(void* const* d_in, const int* in_sizes, int n_in,
                              void* d_out, int out_size, void* d_ws, size_t ws_size,
                              hipStream_t stream) {
    const float* q = (const float*)d_in[0];
    const float* k = (const float*)d_in[1];
    const float* v = (const float*)d_in[2];
    float* out = (float*)d_out;
    la_kernel<<<dim3(64 * 64), dim3(256), 0, stream>>>(q, k, v, out);
}